// Round 6
// baseline (221.061 us; speedup 1.0000x reference)
//
#include <hip/hip_runtime.h>

// W2LossConst: per-trace  sum_i w_i * (t_i - spline_b(F_b[t_i]))^2 * f_b[t_i] * dt
//   F = cumulative trapezoid of f; thread-local exact recurrence
//   F += 0.5*dt*(f[i-1]+f[i]) seeded from a block prefix-scan of f sums.
//
// LDS-issue-bound analysis (R4): the divergent per-iteration interval reload
// was ~50% of LDS ops. Fix: each thread pre-loads a TWO-interval register
// window (c0/c1 + bounds); inner loop selects via cndmask — no LDS, no
// divergence. Rare (~3% of threads) >=2-crossing fallback re-centers from LDS.
// waveoff: shfl-scan (6 ds-ops) replaces serial per-wave LDS loop.
// 512 threads x 16 samples: halves wave count -> scan/reduce overhead amortizes.

#define NT 8192
#define K 128
#define NTHREADS 512
#define ELEMS (NT / NTHREADS)   // 16 samples per thread
#define NWAVES (NTHREADS / 64)  // 8 waves
#define LUTG 256                // uniform search-LUT cells over [0,1]

__global__ __launch_bounds__(NTHREADS, 4) void w2loss_kernel(
    const float* __restrict__ f,
    const float* __restrict__ t,
    const float* __restrict__ knots,
    const float* __restrict__ coeffs,
    float* __restrict__ out)
{
    const int b    = blockIdx.x;
    const int tid  = threadIdx.x;
    const int lane = tid & 63;
    const int wave = tid >> 6;

    __shared__ float  s_knots[K];
    __shared__ float4 s_coeffs[K - 1];
    __shared__ int    s_lut[LUTG];
    __shared__ float  s_wsum[NWAVES];
    __shared__ float  s_wred[NWAVES];
    __shared__ float  s_f0;

    // ---- stage per-trace spline tables in LDS ----
    if (tid < K) s_knots[tid] = knots[(size_t)b * K + tid];
    if (tid < K - 1)
        s_coeffs[tid] =
            reinterpret_cast<const float4*>(coeffs + (size_t)b * (K - 1) * 4)[tid];

    // ---- load this thread's 16 contiguous f samples into registers ----
    const float4* fb4 =
        reinterpret_cast<const float4*>(f + (size_t)b * NT + tid * ELEMS);
    float fv[ELEMS];
#pragma unroll
    for (int i = 0; i < ELEMS / 4; ++i) {
        float4 v = fb4[i];
        fv[4 * i + 0] = v.x; fv[4 * i + 1] = v.y;
        fv[4 * i + 2] = v.z; fv[4 * i + 3] = v.w;
    }

    float local = 0.f;
#pragma unroll
    for (int i = 0; i < ELEMS; ++i) local += fv[i];

    // ---- inclusive wave scan of per-thread sums ----
    float scan = local;
#pragma unroll
    for (int d = 1; d < 64; d <<= 1) {
        float up = __shfl_up(scan, d, 64);
        if (lane >= d) scan += up;
    }
    if (lane == 63) s_wsum[wave] = scan;
    if (tid == 0)  s_f0 = fv[0];
    __syncthreads();                      // knots, coeffs, wsum, f0 visible

    // ---- build uniform search LUT: lut[g] = max idx with knots[idx] <= g/G ----
    if (tid < LUTG) {
        float gval = (float)tid * (1.0f / (float)LUTG);
        int p = 0;
#pragma unroll
        for (int step = 64; step >= 1; step >>= 1) {
            int np = p + step;
            if (np <= K - 1 && s_knots[np] <= gval) p = np;
        }
        s_lut[tid] = p;                   // always <= K-2 (knots[K-1] > 255/256)
    }
    __syncthreads();                      // LUT visible

    // ---- waveoff: one LDS read + shfl scan over the 8 wave sums ----
    float wv = (lane < NWAVES) ? s_wsum[lane] : 0.f;
#pragma unroll
    for (int d = 1; d < NWAVES; d <<= 1) {
        float up = __shfl_up(wv, d, 64);
        if (lane >= d) wv += up;
    }
    const float waveoff = (wave == 0) ? 0.f : __shfl(wv, wave - 1, 64);

    const float f0      = s_f0;
    const float dt      = t[1] - t[0];    // uniform grid; t_i == i*dt
    const float half_dt = 0.5f * dt;

    // thread's first-sample CDF value from the block scan
    const float S_incl_first = waveoff + (scan - local) + fv[0];
    float F = (S_incl_first - 0.5f * (f0 + fv[0])) * dt;

    const int   base = tid * ELEMS;
    const float tb   = (float)base * dt;

    // ---- two-interval register window [i0, i0+1] ----
    int g  = (int)(F * (float)LUTG);
    g      = g > (LUTG - 1) ? (LUTG - 1) : (g < 0 ? 0 : g);
    int i0 = s_lut[g];
    while (i0 < K - 2 && s_knots[i0 + 1] <= F) ++i0;
    float  kn0_lo = s_knots[i0];
    float  kn0_hi = s_knots[i0 + 1];
    float4 c0     = s_coeffs[i0];
    int    j1     = (i0 < K - 2) ? i0 + 1 : K - 2;
    float4 c1     = s_coeffs[j1];
    float  kn1_hi = (i0 + 2 <= K - 1) ? s_knots[i0 + 2] : 3.4e38f;

    float acc, term_first, term_last = 0.f;
    {   // first sample: walk guarantees F in [kn0_lo, kn0_hi)
        float dx = F - kn0_lo;
        float sp = c0.x + dx * (c0.y + dx * (c0.z + dx * c0.w));
        float d0 = tb - sp;
        term_first = d0 * d0 * fv[0];
        acc = term_first;
    }

#pragma unroll
    for (int i = 1; i < ELEMS; ++i) {
        F = fmaf(fv[i - 1] + fv[i], half_dt, F);   // exact trapezoid recurrence

        if (kn1_hi <= F) {                         // rare: window exhausted
            int idx = i0 + 2;
            while (idx < K - 2 && s_knots[idx + 1] <= F) ++idx;
            i0     = idx;
            kn0_lo = s_knots[i0];
            kn0_hi = s_knots[i0 + 1];
            c0     = s_coeffs[i0];
            j1     = (i0 < K - 2) ? i0 + 1 : K - 2;
            c1     = s_coeffs[j1];
            kn1_hi = (i0 + 2 <= K - 1) ? s_knots[i0 + 2] : 3.4e38f;
        }

        // branchless interval select (cndmask, no LDS)
        bool  use1 = (kn0_hi <= F);
        float klo  = use1 ? kn0_hi : kn0_lo;
        float cx   = use1 ? c1.x : c0.x;
        float cy   = use1 ? c1.y : c0.y;
        float cz   = use1 ? c1.z : c0.z;
        float cw   = use1 ? c1.w : c0.w;

        float dx = F - klo;
        float sp = cx + dx * (cy + dx * (cz + dx * cw));
        float tt = fmaf((float)i, dt, tb);
        float d  = tt - sp;
        float term = d * d * fv[i];
        acc += term;
        if (i == ELEMS - 1) term_last = term;
    }

    // endpoint trapezoid weights (0.5) applied as post-corrections
    if (base == 0)          acc -= 0.5f * term_first;
    if (base + ELEMS == NT) acc -= 0.5f * term_last;

    // ---- block reduction ----
#pragma unroll
    for (int d = 32; d >= 1; d >>= 1) acc += __shfl_down(acc, d, 64);
    if (lane == 0) s_wred[wave] = acc;
    __syncthreads();
    if (tid == 0) {
        float r = 0.f;
#pragma unroll
        for (int w = 0; w < NWAVES; ++w) r += s_wred[w];
        out[b] = r * dt;
    }
}

extern "C" void kernel_launch(void* const* d_in, const int* in_sizes, int n_in,
                              void* d_out, int out_size, void* d_ws, size_t ws_size,
                              hipStream_t stream) {
    const float* f      = (const float*)d_in[0];
    const float* t      = (const float*)d_in[1];
    const float* knots  = (const float*)d_in[2];
    const float* coeffs = (const float*)d_in[3];
    float* out          = (float*)d_out;

    const int Btr = in_sizes[0] / NT;   // 2048 traces
    w2loss_kernel<<<Btr, NTHREADS, 0, stream>>>(f, t, knots, coeffs, out);
}

// Round 10
// 121.764 us; speedup vs baseline: 1.8155x; 1.8155x over previous
//
#include <hip/hip_runtime.h>

// W2LossConst: per-trace  sum_i w_i * (t_i - spline_b(F_b[t_i]))^2 * f_b[t_i] * dt
//   F = cumulative trapezoid of f; thread-local exact recurrence
//   F += 0.5*dt*(f[i-1]+f[i]) seeded from a block prefix-scan of f sums.
//
// R6 post-mortem: __launch_bounds__(512,4) capped VGPR at 64 -> fv[16]+window
// state spilled to scratch (204MB fetch + 348MB write, kernel 142us).
// Fix: no min-waves clamp; ~90-110 VGPR -> 4 waves/SIMD, zero scratch.
// Inner loop: TWO-interval register window (c0/c1 + bounds), cndmask select,
// no LDS, no divergence; rare >=2-crossing fallback re-centers from LDS.

#define NT 8192
#define K 128
#define NTHREADS 512
#define ELEMS (NT / NTHREADS)   // 16 samples per thread
#define NWAVES (NTHREADS / 64)  // 8 waves
#define LUTG 256                // uniform search-LUT cells over [0,1]

__global__ __launch_bounds__(NTHREADS) void w2loss_kernel(
    const float* __restrict__ f,
    const float* __restrict__ t,
    const float* __restrict__ knots,
    const float* __restrict__ coeffs,
    float* __restrict__ out)
{
    const int b    = blockIdx.x;
    const int tid  = threadIdx.x;
    const int lane = tid & 63;
    const int wave = tid >> 6;

    __shared__ float  s_knots[K];
    __shared__ float4 s_coeffs[K - 1];
    __shared__ int    s_lut[LUTG];
    __shared__ float  s_wsum[NWAVES];
    __shared__ float  s_wred[NWAVES];
    __shared__ float  s_f0;

    // ---- stage per-trace spline tables in LDS ----
    if (tid < K) s_knots[tid] = knots[(size_t)b * K + tid];
    if (tid < K - 1)
        s_coeffs[tid] =
            reinterpret_cast<const float4*>(coeffs + (size_t)b * (K - 1) * 4)[tid];

    // ---- load this thread's 16 contiguous f samples into registers ----
    const float4* fb4 =
        reinterpret_cast<const float4*>(f + (size_t)b * NT + tid * ELEMS);
    float fv[ELEMS];
#pragma unroll
    for (int i = 0; i < ELEMS / 4; ++i) {
        float4 v = fb4[i];
        fv[4 * i + 0] = v.x; fv[4 * i + 1] = v.y;
        fv[4 * i + 2] = v.z; fv[4 * i + 3] = v.w;
    }

    float local = 0.f;
#pragma unroll
    for (int i = 0; i < ELEMS; ++i) local += fv[i];

    // ---- inclusive wave scan of per-thread sums ----
    float scan = local;
#pragma unroll
    for (int d = 1; d < 64; d <<= 1) {
        float up = __shfl_up(scan, d, 64);
        if (lane >= d) scan += up;
    }
    if (lane == 63) s_wsum[wave] = scan;
    if (tid == 0)  s_f0 = fv[0];
    __syncthreads();                      // knots, coeffs, wsum, f0 visible

    // ---- build uniform search LUT: lut[g] = max idx with knots[idx] <= g/G ----
    if (tid < LUTG) {
        float gval = (float)tid * (1.0f / (float)LUTG);
        int p = 0;
#pragma unroll
        for (int step = 64; step >= 1; step >>= 1) {
            int np = p + step;
            if (np <= K - 1 && s_knots[np] <= gval) p = np;
        }
        s_lut[tid] = p;                   // always <= K-2 (knots[K-1] > 255/256)
    }
    __syncthreads();                      // LUT visible

    // ---- waveoff: one LDS read + shfl scan over the 8 wave sums ----
    float wv = (lane < NWAVES) ? s_wsum[lane] : 0.f;
#pragma unroll
    for (int d = 1; d < NWAVES; d <<= 1) {
        float up = __shfl_up(wv, d, 64);
        if (lane >= d) wv += up;
    }
    const float waveoff = (wave == 0) ? 0.f : __shfl(wv, wave - 1, 64);

    const float f0      = s_f0;
    const float dt      = t[1] - t[0];    // uniform grid; t_i == i*dt
    const float half_dt = 0.5f * dt;

    // thread's first-sample CDF value from the block scan
    const float S_incl_first = waveoff + (scan - local) + fv[0];
    float F = (S_incl_first - 0.5f * (f0 + fv[0])) * dt;

    const int   base = tid * ELEMS;
    const float tb   = (float)base * dt;

    // ---- two-interval register window [i0, i0+1] ----
    int g  = (int)(F * (float)LUTG);
    g      = g > (LUTG - 1) ? (LUTG - 1) : (g < 0 ? 0 : g);
    int i0 = s_lut[g];
    while (i0 < K - 2 && s_knots[i0 + 1] <= F) ++i0;
    float  kn0_lo = s_knots[i0];
    float  kn0_hi = s_knots[i0 + 1];
    float4 c0     = s_coeffs[i0];
    int    j1     = (i0 < K - 2) ? i0 + 1 : K - 2;
    float4 c1     = s_coeffs[j1];
    float  kn1_hi = (i0 + 2 <= K - 1) ? s_knots[i0 + 2] : 3.4e38f;

    float acc, term_first, term_last = 0.f;
    {   // first sample: walk guarantees F in [kn0_lo, kn0_hi)
        float dx = F - kn0_lo;
        float sp = c0.x + dx * (c0.y + dx * (c0.z + dx * c0.w));
        float d0 = tb - sp;
        term_first = d0 * d0 * fv[0];
        acc = term_first;
    }

#pragma unroll
    for (int i = 1; i < ELEMS; ++i) {
        F = fmaf(fv[i - 1] + fv[i], half_dt, F);   // exact trapezoid recurrence

        if (kn1_hi <= F) {                         // rare: window exhausted
            int idx = i0 + 2;
            while (idx < K - 2 && s_knots[idx + 1] <= F) ++idx;
            i0     = idx;
            kn0_lo = s_knots[i0];
            kn0_hi = s_knots[i0 + 1];
            c0     = s_coeffs[i0];
            j1     = (i0 < K - 2) ? i0 + 1 : K - 2;
            c1     = s_coeffs[j1];
            kn1_hi = (i0 + 2 <= K - 1) ? s_knots[i0 + 2] : 3.4e38f;
        }

        // branchless interval select (cndmask, no LDS)
        bool  use1 = (kn0_hi <= F);
        float klo  = use1 ? kn0_hi : kn0_lo;
        float cx   = use1 ? c1.x : c0.x;
        float cy   = use1 ? c1.y : c0.y;
        float cz   = use1 ? c1.z : c0.z;
        float cw   = use1 ? c1.w : c0.w;

        float dx = F - klo;
        float sp = cx + dx * (cy + dx * (cz + dx * cw));
        float tt = fmaf((float)i, dt, tb);
        float d  = tt - sp;
        float term = d * d * fv[i];
        acc += term;
        if (i == ELEMS - 1) term_last = term;
    }

    // endpoint trapezoid weights (0.5) applied as post-corrections
    if (base == 0)          acc -= 0.5f * term_first;
    if (base + ELEMS == NT) acc -= 0.5f * term_last;

    // ---- block reduction ----
#pragma unroll
    for (int d = 32; d >= 1; d >>= 1) acc += __shfl_down(acc, d, 64);
    if (lane == 0) s_wred[wave] = acc;
    __syncthreads();
    if (tid == 0) {
        float r = 0.f;
#pragma unroll
        for (int w = 0; w < NWAVES; ++w) r += s_wred[w];
        out[b] = r * dt;
    }
}

extern "C" void kernel_launch(void* const* d_in, const int* in_sizes, int n_in,
                              void* d_out, int out_size, void* d_ws, size_t ws_size,
                              hipStream_t stream) {
    const float* f      = (const float*)d_in[0];
    const float* t      = (const float*)d_in[1];
    const float* knots  = (const float*)d_in[2];
    const float* coeffs = (const float*)d_in[3];
    float* out          = (float*)d_out;

    const int Btr = in_sizes[0] / NT;   // 2048 traces
    w2loss_kernel<<<Btr, NTHREADS, 0, stream>>>(f, t, knots, coeffs, out);
}